// Round 9
// baseline (267.620 us; speedup 1.0000x reference)
//
#include <hip/hip_runtime.h>
#include <math.h>

// Problem constants (fixed by reference setup_inputs)
#define BATCH 4
#define SEQ   1024
#define DM    1024       // d_model
#define NH    16         // heads
#define DH    64         // head dim
#define BT    (BATCH*SEQ)   // 4096 GEMM rows

typedef _Float16 f16x8 __attribute__((ext_vector_type(8)));
typedef _Float16 f16x4 __attribute__((ext_vector_type(4)));
typedef float    f32x4 __attribute__((ext_vector_type(4)));

// async global->LDS, 16B per lane; LDS dest is wave-uniform base + lane*16
#define GLL16(ldsdst, gsrc) \
  __builtin_amdgcn_global_load_lds((const __attribute__((address_space(1))) void*)(gsrc), \
                                   (__attribute__((address_space(3))) void*)(ldsdst), 16, 0, 0)

// ---------------------------------------------------------------------------
// fp32 -> f16 elementwise (x conversion), float4 -> f16x4
// ---------------------------------------------------------------------------
__global__ __launch_bounds__(256) void cvt_x(const float* __restrict__ x,
                                             _Float16* __restrict__ xh, int nquads)
{
    int i = blockIdx.x * blockDim.x + threadIdx.x;
    for (; i < nquads; i += gridDim.x * blockDim.x) {
        float4 f = ((const float4*)x)[i];
        f16x4 h;
        h[0] = (_Float16)f.x; h[1] = (_Float16)f.y;
        h[2] = (_Float16)f.z; h[3] = (_Float16)f.w;
        ((f16x4*)xh)[i] = h;
    }
}

// ---------------------------------------------------------------------------
// W [1024 k][1024 n] fp32  ->  Wt [1024 n][1024 k] f16   (4 weights, grid.z)
// ---------------------------------------------------------------------------
__global__ __launch_bounds__(256) void cvt_wT(
    const float* __restrict__ W0, const float* __restrict__ W1,
    const float* __restrict__ W2, const float* __restrict__ W3,
    _Float16* __restrict__ T0, _Float16* __restrict__ T1,
    _Float16* __restrict__ T2, _Float16* __restrict__ T3)
{
    __shared__ _Float16 tile[64][72];
    const int z = blockIdx.z;
    const float* W = (z == 0) ? W0 : (z == 1) ? W1 : (z == 2) ? W2 : W3;
    _Float16*    T = (z == 0) ? T0 : (z == 1) ? T1 : (z == 2) ? T2 : T3;
    const int n0 = blockIdx.x * 64;
    const int k0 = blockIdx.y * 64;
    const int tid = threadIdx.x;
#pragma unroll
    for (int p = 0; p < 4; ++p) {
        int r = (tid >> 4) + p * 16;           // k within tile
        int c = (tid & 15) * 4;                // n within tile
        float4 f = *(const float4*)&W[(size_t)(k0 + r) * DM + n0 + c];
        f16x4 h;
        h[0] = (_Float16)f.x; h[1] = (_Float16)f.y;
        h[2] = (_Float16)f.z; h[3] = (_Float16)f.w;
        *(f16x4*)&tile[r][c] = h;
    }
    __syncthreads();
#pragma unroll
    for (int p = 0; p < 2; ++p) {
        int nr = (tid >> 3) + p * 32;          // n within tile
        int kc = (tid & 7) * 8;                // k within tile
        f16x8 vv;
#pragma unroll
        for (int i = 0; i < 8; ++i) vv[i] = tile[kc + i][nr];
        *(f16x8*)&T[(size_t)(n0 + nr) * DM + k0 + kc] = vv;
    }
}

// ---------------------------------------------------------------------------
// f16 MFMA GEMM, m97 structure: 128x128 tile, BK=32, 4 waves, 4x4 16x16x32
// frags per wave, global_load_lds staging (linear LDS), 2-barrier K-loop.
// A [4096][1024] f16 row-major; Bt [N][1024] f16 (transposed weight).
// MODE 1: QKV fused (grid.x = 24: 8 n-tiles each for q,k,v), f16 out in
//         (B,H,T,dh) layout, q scaled by 1/64.
// MODE 0: Wo (grid.x = 8), fp32 out row-major + bias.
// ---------------------------------------------------------------------------
template<int MODE>
__global__ __launch_bounds__(256) void gemm_mfma(
    const _Float16* __restrict__ A,
    const _Float16* __restrict__ B0, const _Float16* __restrict__ B1,
    const _Float16* __restrict__ B2,
    void* __restrict__ o0, void* __restrict__ o1, void* __restrict__ o2,
    const float* __restrict__ bias)
{
    __shared__ _Float16 As[128 * 32];
    __shared__ _Float16 Bs[128 * 32];

    const int tid = threadIdx.x;
    const int w   = tid >> 6;          // wave 0..3
    const int ln  = tid & 63;
    const int l15 = ln & 15;
    const int lg  = ln >> 4;           // 0..3
    const int wr  = w >> 1;            // wave row quadrant
    const int wc  = w & 1;             // wave col quadrant
    const int which = MODE ? (blockIdx.x >> 3) : 0;     // 0:q 1:k 2:v
    const int nl  = (blockIdx.x & 7) * 128;
    const int m0  = blockIdx.y * 128;

    const _Float16* Bt = (which == 0) ? B0 : (which == 1 ? B1 : B2);

    // staging: wave w covers rows w*32..w*32+31 of each tile (2 issues each)
    const int srow = ln >> 2;          // 0..15
    const int scol = (ln & 3) * 8;     // halves
    const _Float16* ga = A  + (size_t)(m0 + w * 32 + srow) * DM + scol;
    const _Float16* gb = Bt + (size_t)(nl + w * 32 + srow) * DM + scol;
    _Float16* la0 = &As[(w * 32 +  0) * 32];
    _Float16* la1 = &As[(w * 32 + 16) * 32];
    _Float16* lb0 = &Bs[(w * 32 +  0) * 32];
    _Float16* lb1 = &Bs[(w * 32 + 16) * 32];

    f32x4 acc[4][4];
#pragma unroll
    for (int i = 0; i < 4; ++i)
#pragma unroll
        for (int j = 0; j < 4; ++j) acc[i][j] = (f32x4){0.f, 0.f, 0.f, 0.f};

    for (int k0 = 0; k0 < DM; k0 += 32) {
        GLL16(la0, ga + k0);
        GLL16(la1, ga + k0 + (size_t)16 * DM);
        GLL16(lb0, gb + k0);
        GLL16(lb1, gb + k0 + (size_t)16 * DM);
        __syncthreads();               // drains vmcnt: tiles staged

        f16x8 af[4], bf[4];
#pragma unroll
        for (int i = 0; i < 4; ++i)
            af[i] = *(const f16x8*)&As[(wr * 64 + i * 16 + l15) * 32 + lg * 8];
#pragma unroll
        for (int j = 0; j < 4; ++j)
            bf[j] = *(const f16x8*)&Bs[(wc * 64 + j * 16 + l15) * 32 + lg * 8];
#pragma unroll
        for (int i = 0; i < 4; ++i)
#pragma unroll
            for (int j = 0; j < 4; ++j)
                acc[i][j] = __builtin_amdgcn_mfma_f32_16x16x32_f16(af[i], bf[j], acc[i][j], 0, 0, 0);
        __syncthreads();               // all reads done before next overwrite
    }

    if (MODE == 1) {
        _Float16* outp = (which == 0) ? (_Float16*)o0
                        : (which == 1) ? (_Float16*)o1 : (_Float16*)o2;
        const float scale = (which == 0) ? 0.015625f : 1.0f;   // Q /= 64
#pragma unroll
        for (int i = 0; i < 4; ++i)
#pragma unroll
            for (int j = 0; j < 4; ++j) {
                int n  = nl + wc * 64 + j * 16 + l15;
                int hh = n >> 6, d = n & 63;
#pragma unroll
                for (int r = 0; r < 4; ++r) {
                    int m  = m0 + wr * 64 + i * 16 + lg * 4 + r;
                    int b_ = m >> 10, t_ = m & 1023;
                    outp[(((size_t)(b_ * NH + hh)) * SEQ + t_) * DH + d] =
                        (_Float16)(acc[i][j][r] * scale);
                }
            }
    } else {
        float* outp = (float*)o0;
#pragma unroll
        for (int i = 0; i < 4; ++i)
#pragma unroll
            for (int j = 0; j < 4; ++j) {
                int n = nl + wc * 64 + j * 16 + l15;
                float bz = bias[n];
#pragma unroll
                for (int r = 0; r < 4; ++r) {
                    int m = m0 + wr * 64 + i * 16 + lg * 4 + r;
                    outp[(size_t)m * DM + n] = acc[i][j][r] + bz;
                }
            }
    }
}

// ---------------------------------------------------------------------------
// V [bh][1024 t][64 d] f16  ->  Vt [bh][64 d][1024 t] f16
// ---------------------------------------------------------------------------
__global__ __launch_bounds__(256) void vtranspose(const _Float16* __restrict__ V,
                                                  _Float16* __restrict__ Vt)
{
    __shared__ _Float16 tile[64][72];
    const int bh = blockIdx.y;
    const int t0 = blockIdx.x * 64;
    const int tid = threadIdx.x;
    const int r = tid >> 3;          // 0..31
    const int c = (tid & 7) * 8;     // 0..56
    const size_t base = (size_t)bh * (SEQ * DH);
#pragma unroll
    for (int p = 0; p < 2; ++p) {
        int row = r + p * 32;
        *(f16x8*)&tile[row][c] = *(const f16x8*)&V[base + (size_t)(t0 + row) * DH + c];
    }
    __syncthreads();
#pragma unroll
    for (int p = 0; p < 2; ++p) {
        int d = r + p * 32;
        f16x8 vv;
#pragma unroll
        for (int i = 0; i < 8; ++i) vv[i] = tile[c + i][d];
        *(f16x8*)&Vt[base + (size_t)d * SEQ + t0 + c] = vv;
    }
}

// ---------------------------------------------------------------------------
// Flash attention, f16 MFMA (16x16x32), causal + rel-pos bias, SPLIT-KV.
// Grid (16 qt, 64 bh), 512 threads = 8 waves = 4 jobs x 2 kv-splits.
// Job j (waves 2j, 2j+1) owns q-rows qt*64 + j*16 .. +15; split s = w&1
// processes kv-tiles kt = s, s+2, ... (online softmax is subset-invariant).
// 8192 total waves -> 100% occupancy cap (was 50%).
// Merge: odd wave stores (m, l, acc-as-f16) in its own Pb region; one
// barrier; even wave rescales and combines, then writes output.
// qt = 15 - blockIdx.x so heaviest blocks launch first.
// ---------------------------------------------------------------------------
__global__ __launch_bounds__(512) void attn_mfma(
    const _Float16* __restrict__ Q,   // [bh][1024][64], pre-scaled by 1/64
    const _Float16* __restrict__ K,   // [bh][1024][64]
    const _Float16* __restrict__ Vt,  // [bh][64][1024]
    const float* __restrict__ rpb,    // [16][1024]
    _Float16* __restrict__ ao)        // [b][t][h*64+d] f16
{
    const int qt  = 15 - blockIdx.x;  // 0..15, heavy first
    const int bh  = blockIdx.y;       // 0..63
    const int b_  = bh >> 4;
    const int h_  = bh & 15;
    const int tid = threadIdx.x;
    const int w   = tid >> 6;         // wave 0..7
    const int job = w >> 1;           // 0..3
    const int s   = w & 1;            // kv split
    const int ln  = tid & 63;
    const int l15 = ln & 15;
    const int lg  = ln >> 4;          // 0..3

    __shared__ _Float16 Pb[8][16][72];   // per-wave P buffer / merge buffer
    __shared__ float mls[4][64][8];      // [job][lane][m0..3, l0..3] from odd wave
    __shared__ float rpb_s[SEQ];

    // stage this head's rpb row (512 threads x 2 floats)
    *(float2*)&rpb_s[tid * 2] = *(const float2*)&rpb[h_ * SEQ + tid * 2];
    __syncthreads();

    const size_t qkb = (size_t)bh * (SEQ * DH);
    const int qr0 = qt * 64 + job * 16;

    f16x8 qa0, qa1;
    {
        const _Float16* qp = Q + qkb + (size_t)(qr0 + l15) * DH + lg * 8;
        qa0 = *(const f16x8*)qp;
        qa1 = *(const f16x8*)(qp + 32);
    }
    f32x4 acc[4];
    float mrow[4], lrow[4];
#pragma unroll
    for (int t = 0; t < 4; ++t) {
        acc[t] = (f32x4){0.f, 0.f, 0.f, 0.f};
        mrow[t] = -INFINITY;
        lrow[t] = 0.f;
    }
    const int ibase = qr0 + lg * 4;   // q row for reg r is ibase + r

#pragma unroll 1
    for (int kt = s; kt <= qt; kt += 2) {
        // ---- S = Q K^T (4 kv sub-tiles of 16) ----
        const _Float16* kp = K + qkb + (size_t)(kt * 64 + l15) * DH + lg * 8;
        f32x4 sv[4];
#pragma unroll
        for (int st = 0; st < 4; ++st) {
            f16x8 kb0 = *(const f16x8*)(kp + st * 16 * DH);
            f16x8 kb1 = *(const f16x8*)(kp + st * 16 * DH + 32);
            f32x4 z = (f32x4){0.f, 0.f, 0.f, 0.f};
            z = __builtin_amdgcn_mfma_f32_16x16x32_f16(qa0, kb0, z, 0, 0, 0);
            z = __builtin_amdgcn_mfma_f32_16x16x32_f16(qa1, kb1, z, 0, 0, 0);
            sv[st] = z;
        }
        // ---- bias + causal mask + tile max ----
        // idx = 1023 - i + j ; masked <=> idx > 1023 (j > i). idx >= 0 always.
        const int bidx = 1023 - ibase + l15 + kt * 64;
        float tm[4] = {-INFINITY, -INFINITY, -INFINITY, -INFINITY};
#pragma unroll
        for (int st = 0; st < 4; ++st)
#pragma unroll
            for (int r = 0; r < 4; ++r) {
                int idx = bidx + st * 16 - r;
                float bv = rpb_s[idx <= 1023 ? idx : 1023];
                float val = (idx <= 1023) ? fmaf(bv, 0.015625f, sv[st][r]) : -INFINITY;
                sv[st][r] = val;
                tm[r] = fmaxf(tm[r], val);
            }
        // ---- online softmax (reduce over 16 kv lanes) ----
#pragma unroll
        for (int r = 0; r < 4; ++r) {
            tm[r] = fmaxf(tm[r], __shfl_xor(tm[r], 1, 16));
            tm[r] = fmaxf(tm[r], __shfl_xor(tm[r], 2, 16));
            tm[r] = fmaxf(tm[r], __shfl_xor(tm[r], 4, 16));
            tm[r] = fmaxf(tm[r], __shfl_xor(tm[r], 8, 16));
        }
        float corr[4], psum[4];
#pragma unroll
        for (int r = 0; r < 4; ++r) {
            float mn = fmaxf(mrow[r], tm[r]);
            corr[r]  = __expf(mrow[r] - mn);
            mrow[r]  = mn;
            psum[r]  = 0.f;
        }
#pragma unroll
        for (int st = 0; st < 4; ++st)
#pragma unroll
            for (int r = 0; r < 4; ++r) {
                float p = __expf(sv[st][r] - mrow[r]);
                sv[st][r] = p;
                psum[r] += p;
            }
#pragma unroll
        for (int r = 0; r < 4; ++r) {
            psum[r] += __shfl_xor(psum[r], 1, 16);
            psum[r] += __shfl_xor(psum[r], 2, 16);
            psum[r] += __shfl_xor(psum[r], 4, 16);
            psum[r] += __shfl_xor(psum[r], 8, 16);
            lrow[r] = lrow[r] * corr[r] + psum[r];
        }
#pragma unroll
        for (int t = 0; t < 4; ++t) {
            acc[t][0] *= corr[0]; acc[t][1] *= corr[1];
            acc[t][2] *= corr[2]; acc[t][3] *= corr[3];
        }
        // ---- P -> per-wave LDS (S layout -> A-frag layout) ----
#pragma unroll
        for (int st = 0; st < 4; ++st)
#pragma unroll
            for (int r = 0; r < 4; ++r)
                Pb[w][lg * 4 + r][st * 16 + l15] = (_Float16)sv[st][r];
        // P written/read by the same wave -> no barrier needed
        f16x8 pa0 = *(const f16x8*)&Pb[w][l15][lg * 8];
        f16x8 pa1 = *(const f16x8*)&Pb[w][l15][32 + lg * 8];
        const _Float16* vp = Vt + qkb + (size_t)l15 * SEQ + kt * 64 + lg * 8;
#pragma unroll
        for (int dt = 0; dt < 4; ++dt) {
            f16x8 vb0 = *(const f16x8*)(vp + dt * 16 * SEQ);
            f16x8 vb1 = *(const f16x8*)(vp + dt * 16 * SEQ + 32);
            acc[dt] = __builtin_amdgcn_mfma_f32_16x16x32_f16(pa0, vb0, acc[dt], 0, 0, 0);
            acc[dt] = __builtin_amdgcn_mfma_f32_16x16x32_f16(pa1, vb1, acc[dt], 0, 0, 0);
        }
    }

    // ---- split-kv merge ----
    if (s == 1) {
        _Float16* mb = &Pb[w][0][0];          // own region, 1152 f16 >= 1024
#pragma unroll
        for (int dt = 0; dt < 4; ++dt)
#pragma unroll
            for (int r = 0; r < 4; ++r)
                mb[ln * 16 + dt * 4 + r] = (_Float16)acc[dt][r];
#pragma unroll
        for (int r = 0; r < 4; ++r) {
            mls[job][ln][r]     = mrow[r];
            mls[job][ln][4 + r] = lrow[r];
        }
    }
    __syncthreads();
    if (s == 0) {
        const _Float16* mb = &Pb[w + 1][0][0];
        float c0[4], c1[4];
#pragma unroll
        for (int r = 0; r < 4; ++r) {
            float m1 = mls[job][ln][r];
            float l1 = mls[job][ln][4 + r];
            float mm = fmaxf(mrow[r], m1);
            c0[r] = __expf(mrow[r] - mm);
            c1[r] = __expf(m1 - mm);
            lrow[r] = lrow[r] * c0[r] + l1 * c1[r];
        }
        _Float16* aop = ao + ((size_t)b_ * SEQ + ibase) * DM + h_ * DH + l15;
#pragma unroll
        for (int r = 0; r < 4; ++r) {
            float inv = 1.f / lrow[r];
#pragma unroll
            for (int dt = 0; dt < 4; ++dt) {
                float v = acc[dt][r] * c0[r] + (float)mb[ln * 16 + dt * 4 + r] * c1[r];
                aop[(size_t)r * DM + dt * 16] = (_Float16)(v * inv);
            }
        }
    }
}

// ---------------------------------------------------------------------------
extern "C" void kernel_launch(void* const* d_in, const int* in_sizes, int n_in,
                              void* d_out, int out_size, void* d_ws, size_t ws_size,
                              hipStream_t stream)
{
    (void)in_sizes; (void)n_in; (void)out_size; (void)ws_size;
    const float* x   = (const float*)d_in[0];
    const float* Wq  = (const float*)d_in[1];
    const float* Wk  = (const float*)d_in[2];
    const float* Wv  = (const float*)d_in[3];
    const float* Wo  = (const float*)d_in[4];
    const float* bo  = (const float*)d_in[5];
    const float* rpb = (const float*)d_in[6];
    float* out = (float*)d_out;

    char* ws = (char*)d_ws;
    _Float16* xh  = (_Float16*)(ws);                  // 8 MB
    _Float16* q   = (_Float16*)(ws + (8u  << 20));    // 8 MB
    _Float16* k   = (_Float16*)(ws + (16u << 20));    // 8 MB
    _Float16* v   = (_Float16*)(ws + (24u << 20));    // 8 MB
    _Float16* vt  = (_Float16*)(ws + (32u << 20));    // 8 MB
    _Float16* aoh = (_Float16*)(ws + (40u << 20));    // 8 MB
    _Float16* wqt = (_Float16*)(ws + (48u << 20));    // 2 MB
    _Float16* wkt = (_Float16*)(ws + (50u << 20));    // 2 MB
    _Float16* wvt = (_Float16*)(ws + (52u << 20));    // 2 MB
    _Float16* wot = (_Float16*)(ws + (54u << 20));    // 2 MB

    cvt_x<<<2048, 256, 0, stream>>>(x, xh, BT * DM / 4);
    cvt_wT<<<dim3(16, 16, 4), 256, 0, stream>>>(Wq, Wk, Wv, Wo, wqt, wkt, wvt, wot);
    gemm_mfma<1><<<dim3(24, 32), 256, 0, stream>>>(xh, wqt, wkt, wvt, q, k, v, nullptr);
    vtranspose<<<dim3(SEQ / 64, BATCH * NH), 256, 0, stream>>>(v, vt);
    attn_mfma<<<dim3(16, BATCH * NH), 512, 0, stream>>>(q, k, vt, rpb, aoh);
    gemm_mfma<0><<<dim3(8, 32), 256, 0, stream>>>(aoh, wot, nullptr, nullptr, out, nullptr, nullptr, bo);
}

// Round 10
// 228.716 us; speedup vs baseline: 1.1701x; 1.1701x over previous
//
#include <hip/hip_runtime.h>
#include <math.h>

// Problem constants (fixed by reference setup_inputs)
#define BATCH 4
#define SEQ   1024
#define DM    1024       // d_model
#define NH    16         // heads
#define DH    64         // head dim
#define BT    (BATCH*SEQ)   // 4096 GEMM rows

typedef _Float16 f16x8 __attribute__((ext_vector_type(8)));
typedef _Float16 f16x4 __attribute__((ext_vector_type(4)));
typedef float    f32x4 __attribute__((ext_vector_type(4)));

// async global->LDS, 16B per lane; LDS dest is wave-uniform base + lane*16
#define GLL16(ldsdst, gsrc) \
  __builtin_amdgcn_global_load_lds((const __attribute__((address_space(1))) void*)(gsrc), \
                                   (__attribute__((address_space(3))) void*)(ldsdst), 16, 0, 0)

// ---------------------------------------------------------------------------
// fp32 -> f16 elementwise (x conversion), float4 -> f16x4
// ---------------------------------------------------------------------------
__global__ __launch_bounds__(256) void cvt_x(const float* __restrict__ x,
                                             _Float16* __restrict__ xh, int nquads)
{
    int i = blockIdx.x * blockDim.x + threadIdx.x;
    for (; i < nquads; i += gridDim.x * blockDim.x) {
        float4 f = ((const float4*)x)[i];
        f16x4 h;
        h[0] = (_Float16)f.x; h[1] = (_Float16)f.y;
        h[2] = (_Float16)f.z; h[3] = (_Float16)f.w;
        ((f16x4*)xh)[i] = h;
    }
}

// ---------------------------------------------------------------------------
// W [1024 k][1024 n] fp32  ->  Wt [1024 n][1024 k] f16   (4 weights, grid.z)
// ---------------------------------------------------------------------------
__global__ __launch_bounds__(256) void cvt_wT(
    const float* __restrict__ W0, const float* __restrict__ W1,
    const float* __restrict__ W2, const float* __restrict__ W3,
    _Float16* __restrict__ T0, _Float16* __restrict__ T1,
    _Float16* __restrict__ T2, _Float16* __restrict__ T3)
{
    __shared__ _Float16 tile[64][72];
    const int z = blockIdx.z;
    const float* W = (z == 0) ? W0 : (z == 1) ? W1 : (z == 2) ? W2 : W3;
    _Float16*    T = (z == 0) ? T0 : (z == 1) ? T1 : (z == 2) ? T2 : T3;
    const int n0 = blockIdx.x * 64;
    const int k0 = blockIdx.y * 64;
    const int tid = threadIdx.x;
#pragma unroll
    for (int p = 0; p < 4; ++p) {
        int r = (tid >> 4) + p * 16;           // k within tile
        int c = (tid & 15) * 4;                // n within tile
        float4 f = *(const float4*)&W[(size_t)(k0 + r) * DM + n0 + c];
        f16x4 h;
        h[0] = (_Float16)f.x; h[1] = (_Float16)f.y;
        h[2] = (_Float16)f.z; h[3] = (_Float16)f.w;
        *(f16x4*)&tile[r][c] = h;
    }
    __syncthreads();
#pragma unroll
    for (int p = 0; p < 2; ++p) {
        int nr = (tid >> 3) + p * 32;          // n within tile
        int kc = (tid & 7) * 8;                // k within tile
        f16x8 vv;
#pragma unroll
        for (int i = 0; i < 8; ++i) vv[i] = tile[kc + i][nr];
        *(f16x8*)&T[(size_t)(n0 + nr) * DM + k0 + kc] = vv;
    }
}

// ---------------------------------------------------------------------------
// f16 MFMA GEMM, m97 structure: 128x128 tile, BK=32, 4 waves, 4x4 16x16x32
// frags per wave, global_load_lds staging (linear LDS), 2-barrier K-loop.
// A [4096][1024] f16 row-major; Bt [N][1024] f16 (transposed weight).
// MODE 1: QKV fused (grid.x = 24: 8 n-tiles each for q,k,v), f16 out in
//         (B,H,T,dh) layout, q scaled by 1/64.
// MODE 0: Wo (grid.x = 8), fp32 out row-major + bias.
// ---------------------------------------------------------------------------
template<int MODE>
__global__ __launch_bounds__(256) void gemm_mfma(
    const _Float16* __restrict__ A,
    const _Float16* __restrict__ B0, const _Float16* __restrict__ B1,
    const _Float16* __restrict__ B2,
    void* __restrict__ o0, void* __restrict__ o1, void* __restrict__ o2,
    const float* __restrict__ bias)
{
    __shared__ _Float16 As[128 * 32];
    __shared__ _Float16 Bs[128 * 32];

    const int tid = threadIdx.x;
    const int w   = tid >> 6;          // wave 0..3
    const int ln  = tid & 63;
    const int l15 = ln & 15;
    const int lg  = ln >> 4;           // 0..3
    const int wr  = w >> 1;            // wave row quadrant
    const int wc  = w & 1;             // wave col quadrant
    const int which = MODE ? (blockIdx.x >> 3) : 0;     // 0:q 1:k 2:v
    const int nl  = (blockIdx.x & 7) * 128;
    const int m0  = blockIdx.y * 128;

    const _Float16* Bt = (which == 0) ? B0 : (which == 1 ? B1 : B2);

    // staging: wave w covers rows w*32..w*32+31 of each tile (2 issues each)
    const int srow = ln >> 2;          // 0..15
    const int scol = (ln & 3) * 8;     // halves
    const _Float16* ga = A  + (size_t)(m0 + w * 32 + srow) * DM + scol;
    const _Float16* gb = Bt + (size_t)(nl + w * 32 + srow) * DM + scol;
    _Float16* la0 = &As[(w * 32 +  0) * 32];
    _Float16* la1 = &As[(w * 32 + 16) * 32];
    _Float16* lb0 = &Bs[(w * 32 +  0) * 32];
    _Float16* lb1 = &Bs[(w * 32 + 16) * 32];

    f32x4 acc[4][4];
#pragma unroll
    for (int i = 0; i < 4; ++i)
#pragma unroll
        for (int j = 0; j < 4; ++j) acc[i][j] = (f32x4){0.f, 0.f, 0.f, 0.f};

    for (int k0 = 0; k0 < DM; k0 += 32) {
        GLL16(la0, ga + k0);
        GLL16(la1, ga + k0 + (size_t)16 * DM);
        GLL16(lb0, gb + k0);
        GLL16(lb1, gb + k0 + (size_t)16 * DM);
        __syncthreads();               // drains vmcnt: tiles staged

        f16x8 af[4], bf[4];
#pragma unroll
        for (int i = 0; i < 4; ++i)
            af[i] = *(const f16x8*)&As[(wr * 64 + i * 16 + l15) * 32 + lg * 8];
#pragma unroll
        for (int j = 0; j < 4; ++j)
            bf[j] = *(const f16x8*)&Bs[(wc * 64 + j * 16 + l15) * 32 + lg * 8];
#pragma unroll
        for (int i = 0; i < 4; ++i)
#pragma unroll
            for (int j = 0; j < 4; ++j)
                acc[i][j] = __builtin_amdgcn_mfma_f32_16x16x32_f16(af[i], bf[j], acc[i][j], 0, 0, 0);
        __syncthreads();               // all reads done before next overwrite
    }

    if (MODE == 1) {
        _Float16* outp = (which == 0) ? (_Float16*)o0
                        : (which == 1) ? (_Float16*)o1 : (_Float16*)o2;
        const float scale = (which == 0) ? 0.015625f : 1.0f;   // Q /= 64
#pragma unroll
        for (int i = 0; i < 4; ++i)
#pragma unroll
            for (int j = 0; j < 4; ++j) {
                int n  = nl + wc * 64 + j * 16 + l15;
                int hh = n >> 6, d = n & 63;
#pragma unroll
                for (int r = 0; r < 4; ++r) {
                    int m  = m0 + wr * 64 + i * 16 + lg * 4 + r;
                    int b_ = m >> 10, t_ = m & 1023;
                    outp[(((size_t)(b_ * NH + hh)) * SEQ + t_) * DH + d] =
                        (_Float16)(acc[i][j][r] * scale);
                }
            }
    } else {
        float* outp = (float*)o0;
#pragma unroll
        for (int i = 0; i < 4; ++i)
#pragma unroll
            for (int j = 0; j < 4; ++j) {
                int n = nl + wc * 64 + j * 16 + l15;
                float bz = bias[n];
#pragma unroll
                for (int r = 0; r < 4; ++r) {
                    int m = m0 + wr * 64 + i * 16 + lg * 4 + r;
                    outp[(size_t)m * DM + n] = acc[i][j][r] + bz;
                }
            }
    }
}

// ---------------------------------------------------------------------------
// V [bh][1024 t][64 d] f16  ->  Vt [bh][64 d][1024 t] f16
// ---------------------------------------------------------------------------
__global__ __launch_bounds__(256) void vtranspose(const _Float16* __restrict__ V,
                                                  _Float16* __restrict__ Vt)
{
    __shared__ _Float16 tile[64][72];
    const int bh = blockIdx.y;
    const int t0 = blockIdx.x * 64;
    const int tid = threadIdx.x;
    const int r = tid >> 3;          // 0..31
    const int c = (tid & 7) * 8;     // 0..56
    const size_t base = (size_t)bh * (SEQ * DH);
#pragma unroll
    for (int p = 0; p < 2; ++p) {
        int row = r + p * 32;
        *(f16x8*)&tile[row][c] = *(const f16x8*)&V[base + (size_t)(t0 + row) * DH + c];
    }
    __syncthreads();
#pragma unroll
    for (int p = 0; p < 2; ++p) {
        int d = r + p * 32;
        f16x8 vv;
#pragma unroll
        for (int i = 0; i < 8; ++i) vv[i] = tile[c + i][d];
        *(f16x8*)&Vt[base + (size_t)d * SEQ + t0 + c] = vv;
    }
}

// ---------------------------------------------------------------------------
// Flash attention, f16 MFMA, causal + rel-pos bias, PAIR-AND-SPLIT.
// Grid (8 pairs, 64 bh), 512 threads = 8 waves. Wave (j = w>>1, s = w&1):
// sequentially runs job j (16 q-rows) of qt=pr AND qt=15-pr, each with
// kv-split s (kt = s, s+2, ...). Per-wave work = 9 (s=0) or 8 (s=1) tiles
// for EVERY wave of EVERY block -> uniform load, halved critical path.
// Partials (m, l, acc-as-f16) -> LDS; one barrier; wave w merges output
// (j2 = w>>1, qt2 = w&1 ? 15-pr : pr) with validated 2-way merge math.
// ---------------------------------------------------------------------------
__global__ __launch_bounds__(512) void attn_mfma(
    const _Float16* __restrict__ Q,   // [bh][1024][64], pre-scaled by 1/64
    const _Float16* __restrict__ K,   // [bh][1024][64]
    const _Float16* __restrict__ Vt,  // [bh][64][1024]
    const float* __restrict__ rpb,    // [16][1024]
    _Float16* __restrict__ ao)        // [b][t][h*64+d] f16
{
    const int pr  = blockIdx.x;       // 0..7
    const int bh  = blockIdx.y;       // 0..63
    const int b_  = bh >> 4;
    const int h_  = bh & 15;
    const int tid = threadIdx.x;
    const int w   = tid >> 6;         // wave 0..7
    const int j   = w >> 1;           // job 0..3 (16 q-rows within a qt)
    const int s   = w & 1;            // kv split
    const int ln  = tid & 63;
    const int l15 = ln & 15;
    const int lg  = ln >> 4;          // 0..3

    __shared__ _Float16 Pb[8][16][72];      // per-wave P buffer (18.4 KB)
    __shared__ _Float16 part[8][2][1024];   // [wave][jobidx] partial acc (32 KB)
    __shared__ float    mlb[8][2][16][2];   // [wave][jobidx][row][m,l] (2 KB)
    __shared__ float    rpb_s[SEQ];         // 4 KB

    // stage this head's rpb row (512 threads x 2 floats)
    *(float2*)&rpb_s[tid * 2] = *(const float2*)&rpb[h_ * SEQ + tid * 2];
    __syncthreads();

    const size_t qkb = (size_t)bh * (SEQ * DH);

#pragma unroll 1
    for (int ji = 0; ji < 2; ++ji) {
        const int qt  = ji ? (15 - pr) : pr;
        const int qr0 = qt * 64 + j * 16;
        const int ibase = qr0 + lg * 4;   // q row for reg r is ibase + r

        f16x8 qa0, qa1;
        {
            const _Float16* qp = Q + qkb + (size_t)(qr0 + l15) * DH + lg * 8;
            qa0 = *(const f16x8*)qp;
            qa1 = *(const f16x8*)(qp + 32);
        }
        f32x4 acc[4];
        float mrow[4], lrow[4];
#pragma unroll
        for (int t = 0; t < 4; ++t) {
            acc[t] = (f32x4){0.f, 0.f, 0.f, 0.f};
            mrow[t] = -INFINITY;
            lrow[t] = 0.f;
        }

#pragma unroll 1
        for (int kt = s; kt <= qt; kt += 2) {
            // ---- S = Q K^T (4 kv sub-tiles of 16) ----
            const _Float16* kp = K + qkb + (size_t)(kt * 64 + l15) * DH + lg * 8;
            f32x4 sv[4];
#pragma unroll
            for (int st = 0; st < 4; ++st) {
                f16x8 kb0 = *(const f16x8*)(kp + st * 16 * DH);
                f16x8 kb1 = *(const f16x8*)(kp + st * 16 * DH + 32);
                f32x4 z = (f32x4){0.f, 0.f, 0.f, 0.f};
                z = __builtin_amdgcn_mfma_f32_16x16x32_f16(qa0, kb0, z, 0, 0, 0);
                z = __builtin_amdgcn_mfma_f32_16x16x32_f16(qa1, kb1, z, 0, 0, 0);
                sv[st] = z;
            }
            // ---- bias + causal mask + tile max ----
            // idx = 1023 - i + j ; masked <=> idx > 1023 (j > i). idx >= 0 always.
            const int bidx = 1023 - ibase + l15 + kt * 64;
            float tm[4] = {-INFINITY, -INFINITY, -INFINITY, -INFINITY};
#pragma unroll
            for (int st = 0; st < 4; ++st)
#pragma unroll
                for (int r = 0; r < 4; ++r) {
                    int idx = bidx + st * 16 - r;
                    float bv = rpb_s[idx <= 1023 ? idx : 1023];
                    float val = (idx <= 1023) ? fmaf(bv, 0.015625f, sv[st][r]) : -INFINITY;
                    sv[st][r] = val;
                    tm[r] = fmaxf(tm[r], val);
                }
            // ---- online softmax (reduce over 16 kv lanes) ----
#pragma unroll
            for (int r = 0; r < 4; ++r) {
                tm[r] = fmaxf(tm[r], __shfl_xor(tm[r], 1, 16));
                tm[r] = fmaxf(tm[r], __shfl_xor(tm[r], 2, 16));
                tm[r] = fmaxf(tm[r], __shfl_xor(tm[r], 4, 16));
                tm[r] = fmaxf(tm[r], __shfl_xor(tm[r], 8, 16));
            }
            float corr[4], psum[4];
#pragma unroll
            for (int r = 0; r < 4; ++r) {
                float mn = fmaxf(mrow[r], tm[r]);
                corr[r]  = __expf(mrow[r] - mn);
                mrow[r]  = mn;
                psum[r]  = 0.f;
            }
#pragma unroll
            for (int st = 0; st < 4; ++st)
#pragma unroll
                for (int r = 0; r < 4; ++r) {
                    float p = __expf(sv[st][r] - mrow[r]);
                    sv[st][r] = p;
                    psum[r] += p;
                }
#pragma unroll
            for (int r = 0; r < 4; ++r) {
                psum[r] += __shfl_xor(psum[r], 1, 16);
                psum[r] += __shfl_xor(psum[r], 2, 16);
                psum[r] += __shfl_xor(psum[r], 4, 16);
                psum[r] += __shfl_xor(psum[r], 8, 16);
                lrow[r] = lrow[r] * corr[r] + psum[r];
            }
#pragma unroll
            for (int t = 0; t < 4; ++t) {
                acc[t][0] *= corr[0]; acc[t][1] *= corr[1];
                acc[t][2] *= corr[2]; acc[t][3] *= corr[3];
            }
            // ---- P -> per-wave LDS (S layout -> A-frag layout) ----
#pragma unroll
            for (int st = 0; st < 4; ++st)
#pragma unroll
                for (int r = 0; r < 4; ++r)
                    Pb[w][lg * 4 + r][st * 16 + l15] = (_Float16)sv[st][r];
            // P written/read by the same wave -> no barrier needed
            f16x8 pa0 = *(const f16x8*)&Pb[w][l15][lg * 8];
            f16x8 pa1 = *(const f16x8*)&Pb[w][l15][32 + lg * 8];
            const _Float16* vp = Vt + qkb + (size_t)l15 * SEQ + kt * 64 + lg * 8;
#pragma unroll
            for (int dt = 0; dt < 4; ++dt) {
                f16x8 vb0 = *(const f16x8*)(vp + dt * 16 * SEQ);
                f16x8 vb1 = *(const f16x8*)(vp + dt * 16 * SEQ + 32);
                acc[dt] = __builtin_amdgcn_mfma_f32_16x16x32_f16(pa0, vb0, acc[dt], 0, 0, 0);
                acc[dt] = __builtin_amdgcn_mfma_f32_16x16x32_f16(pa1, vb1, acc[dt], 0, 0, 0);
            }
        }

        // ---- store this job's partial state to LDS ----
#pragma unroll
        for (int dt = 0; dt < 4; ++dt)
#pragma unroll
            for (int r = 0; r < 4; ++r)
                part[w][ji][ln * 16 + dt * 4 + r] = (_Float16)acc[dt][r];
        if (l15 == 0) {
#pragma unroll
            for (int r = 0; r < 4; ++r) {
                mlb[w][ji][lg * 4 + r][0] = mrow[r];
                mlb[w][ji][lg * 4 + r][1] = lrow[r];
            }
        }
    }
    __syncthreads();

    // ---- merge: wave w combines splits for output (j2, qt2) ----
    {
        const int qs  = w & 1;
        const int j2  = w >> 1;
        const int qt2 = qs ? (15 - pr) : pr;
        const int wA  = j2 * 2;        // s=0 partial
        const int wB  = wA + 1;        // s=1 partial
        const int ibase2 = qt2 * 64 + j2 * 16 + lg * 4;
        float c0[4], c1[4], linv[4];
#pragma unroll
        for (int r = 0; r < 4; ++r) {
            float m0 = mlb[wA][qs][lg * 4 + r][0];
            float l0 = mlb[wA][qs][lg * 4 + r][1];
            float m1 = mlb[wB][qs][lg * 4 + r][0];
            float l1 = mlb[wB][qs][lg * 4 + r][1];
            float mm = fmaxf(m0, m1);         // m0 always finite (s=0 nonempty)
            c0[r] = __expf(m0 - mm);
            c1[r] = __expf(m1 - mm);          // empty split: exp(-inf)=0
            linv[r] = 1.f / (l0 * c0[r] + l1 * c1[r]);
        }
        _Float16* aop = ao + ((size_t)b_ * SEQ + ibase2) * DM + h_ * DH + l15;
#pragma unroll
        for (int r = 0; r < 4; ++r)
#pragma unroll
            for (int dt = 0; dt < 4; ++dt) {
                float v = (float)part[wA][qs][ln * 16 + dt * 4 + r] * c0[r]
                        + (float)part[wB][qs][ln * 16 + dt * 4 + r] * c1[r];
                aop[(size_t)r * DM + dt * 16] = (_Float16)(v * linv[r]);
            }
    }
}

// ---------------------------------------------------------------------------
extern "C" void kernel_launch(void* const* d_in, const int* in_sizes, int n_in,
                              void* d_out, int out_size, void* d_ws, size_t ws_size,
                              hipStream_t stream)
{
    (void)in_sizes; (void)n_in; (void)out_size; (void)ws_size;
    const float* x   = (const float*)d_in[0];
    const float* Wq  = (const float*)d_in[1];
    const float* Wk  = (const float*)d_in[2];
    const float* Wv  = (const float*)d_in[3];
    const float* Wo  = (const float*)d_in[4];
    const float* bo  = (const float*)d_in[5];
    const float* rpb = (const float*)d_in[6];
    float* out = (float*)d_out;

    char* ws = (char*)d_ws;
    _Float16* xh  = (_Float16*)(ws);                  // 8 MB
    _Float16* q   = (_Float16*)(ws + (8u  << 20));    // 8 MB
    _Float16* k   = (_Float16*)(ws + (16u << 20));    // 8 MB
    _Float16* v   = (_Float16*)(ws + (24u << 20));    // 8 MB
    _Float16* vt  = (_Float16*)(ws + (32u << 20));    // 8 MB
    _Float16* aoh = (_Float16*)(ws + (40u << 20));    // 8 MB
    _Float16* wqt = (_Float16*)(ws + (48u << 20));    // 2 MB
    _Float16* wkt = (_Float16*)(ws + (50u << 20));    // 2 MB
    _Float16* wvt = (_Float16*)(ws + (52u << 20));    // 2 MB
    _Float16* wot = (_Float16*)(ws + (54u << 20));    // 2 MB

    cvt_x<<<2048, 256, 0, stream>>>(x, xh, BT * DM / 4);
    cvt_wT<<<dim3(16, 16, 4), 256, 0, stream>>>(Wq, Wk, Wv, Wo, wqt, wkt, wvt, wot);
    gemm_mfma<1><<<dim3(24, 32), 256, 0, stream>>>(xh, wqt, wkt, wvt, q, k, v, nullptr);
    vtranspose<<<dim3(SEQ / 64, BATCH * NH), 256, 0, stream>>>(v, vt);
    attn_mfma<<<dim3(8, BATCH * NH), 512, 0, stream>>>(q, k, vt, rpb, aoh);
    gemm_mfma<0><<<dim3(8, 32), 256, 0, stream>>>(aoh, wot, nullptr, nullptr, out, nullptr, nullptr, bo);
}

// Round 11
// 216.111 us; speedup vs baseline: 1.2383x; 1.0583x over previous
//
#include <hip/hip_runtime.h>
#include <math.h>

// Problem constants (fixed by reference setup_inputs)
#define BATCH 4
#define SEQ   1024
#define DM    1024       // d_model
#define NH    16         // heads
#define DH    64         // head dim
#define BT    (BATCH*SEQ)   // 4096 GEMM rows

typedef _Float16 f16x8 __attribute__((ext_vector_type(8)));
typedef _Float16 f16x4 __attribute__((ext_vector_type(4)));
typedef float    f32x4 __attribute__((ext_vector_type(4)));

// async global->LDS, 16B per lane; LDS dest is wave-uniform base + lane*16
#define GLL16(ldsdst, gsrc) \
  __builtin_amdgcn_global_load_lds((const __attribute__((address_space(1))) void*)(gsrc), \
                                   (__attribute__((address_space(3))) void*)(ldsdst), 16, 0, 0)

// ---------------------------------------------------------------------------
// fp32 -> f16 elementwise (x conversion), float4 -> f16x4
// ---------------------------------------------------------------------------
__global__ __launch_bounds__(256) void cvt_x(const float* __restrict__ x,
                                             _Float16* __restrict__ xh, int nquads)
{
    int i = blockIdx.x * blockDim.x + threadIdx.x;
    for (; i < nquads; i += gridDim.x * blockDim.x) {
        float4 f = ((const float4*)x)[i];
        f16x4 h;
        h[0] = (_Float16)f.x; h[1] = (_Float16)f.y;
        h[2] = (_Float16)f.z; h[3] = (_Float16)f.w;
        ((f16x4*)xh)[i] = h;
    }
}

// ---------------------------------------------------------------------------
// W [1024 k][1024 n] fp32  ->  Wt [1024 n][1024 k] f16   (4 weights, grid.z)
// ---------------------------------------------------------------------------
__global__ __launch_bounds__(256) void cvt_wT(
    const float* __restrict__ W0, const float* __restrict__ W1,
    const float* __restrict__ W2, const float* __restrict__ W3,
    _Float16* __restrict__ T0, _Float16* __restrict__ T1,
    _Float16* __restrict__ T2, _Float16* __restrict__ T3)
{
    __shared__ _Float16 tile[64][72];
    const int z = blockIdx.z;
    const float* W = (z == 0) ? W0 : (z == 1) ? W1 : (z == 2) ? W2 : W3;
    _Float16*    T = (z == 0) ? T0 : (z == 1) ? T1 : (z == 2) ? T2 : T3;
    const int n0 = blockIdx.x * 64;
    const int k0 = blockIdx.y * 64;
    const int tid = threadIdx.x;
#pragma unroll
    for (int p = 0; p < 4; ++p) {
        int r = (tid >> 4) + p * 16;           // k within tile
        int c = (tid & 15) * 4;                // n within tile
        float4 f = *(const float4*)&W[(size_t)(k0 + r) * DM + n0 + c];
        f16x4 h;
        h[0] = (_Float16)f.x; h[1] = (_Float16)f.y;
        h[2] = (_Float16)f.z; h[3] = (_Float16)f.w;
        *(f16x4*)&tile[r][c] = h;
    }
    __syncthreads();
#pragma unroll
    for (int p = 0; p < 2; ++p) {
        int nr = (tid >> 3) + p * 32;          // n within tile
        int kc = (tid & 7) * 8;                // k within tile
        f16x8 vv;
#pragma unroll
        for (int i = 0; i < 8; ++i) vv[i] = tile[kc + i][nr];
        *(f16x8*)&T[(size_t)(n0 + nr) * DM + k0 + kc] = vv;
    }
}

// ---------------------------------------------------------------------------
// f16 MFMA GEMM, m97 structure: 128x128 tile, BK=32, 4 waves, 4x4 16x16x32
// frags per wave, global_load_lds staging (linear LDS), 2-barrier K-loop.
// A [4096][1024] f16 row-major; Bt [N][1024] f16 (transposed weight).
// MODE 1: QKV fused (grid.x = 24: 8 n-tiles each for q,k,v), f16 out in
//         (B,H,T,dh) layout, q scaled by 1/64.
// MODE 0: Wo (grid.x = 8), fp32 out row-major + bias.
// ---------------------------------------------------------------------------
template<int MODE>
__global__ __launch_bounds__(256) void gemm_mfma(
    const _Float16* __restrict__ A,
    const _Float16* __restrict__ B0, const _Float16* __restrict__ B1,
    const _Float16* __restrict__ B2,
    void* __restrict__ o0, void* __restrict__ o1, void* __restrict__ o2,
    const float* __restrict__ bias)
{
    __shared__ _Float16 As[128 * 32];
    __shared__ _Float16 Bs[128 * 32];

    const int tid = threadIdx.x;
    const int w   = tid >> 6;          // wave 0..3
    const int ln  = tid & 63;
    const int l15 = ln & 15;
    const int lg  = ln >> 4;           // 0..3
    const int wr  = w >> 1;            // wave row quadrant
    const int wc  = w & 1;             // wave col quadrant
    const int which = MODE ? (blockIdx.x >> 3) : 0;     // 0:q 1:k 2:v
    const int nl  = (blockIdx.x & 7) * 128;
    const int m0  = blockIdx.y * 128;

    const _Float16* Bt = (which == 0) ? B0 : (which == 1 ? B1 : B2);

    // staging: wave w covers rows w*32..w*32+31 of each tile (2 issues each)
    const int srow = ln >> 2;          // 0..15
    const int scol = (ln & 3) * 8;     // halves
    const _Float16* ga = A  + (size_t)(m0 + w * 32 + srow) * DM + scol;
    const _Float16* gb = Bt + (size_t)(nl + w * 32 + srow) * DM + scol;
    _Float16* la0 = &As[(w * 32 +  0) * 32];
    _Float16* la1 = &As[(w * 32 + 16) * 32];
    _Float16* lb0 = &Bs[(w * 32 +  0) * 32];
    _Float16* lb1 = &Bs[(w * 32 + 16) * 32];

    f32x4 acc[4][4];
#pragma unroll
    for (int i = 0; i < 4; ++i)
#pragma unroll
        for (int j = 0; j < 4; ++j) acc[i][j] = (f32x4){0.f, 0.f, 0.f, 0.f};

    for (int k0 = 0; k0 < DM; k0 += 32) {
        GLL16(la0, ga + k0);
        GLL16(la1, ga + k0 + (size_t)16 * DM);
        GLL16(lb0, gb + k0);
        GLL16(lb1, gb + k0 + (size_t)16 * DM);
        __syncthreads();               // drains vmcnt: tiles staged

        f16x8 af[4], bf[4];
#pragma unroll
        for (int i = 0; i < 4; ++i)
            af[i] = *(const f16x8*)&As[(wr * 64 + i * 16 + l15) * 32 + lg * 8];
#pragma unroll
        for (int j = 0; j < 4; ++j)
            bf[j] = *(const f16x8*)&Bs[(wc * 64 + j * 16 + l15) * 32 + lg * 8];
#pragma unroll
        for (int i = 0; i < 4; ++i)
#pragma unroll
            for (int j = 0; j < 4; ++j)
                acc[i][j] = __builtin_amdgcn_mfma_f32_16x16x32_f16(af[i], bf[j], acc[i][j], 0, 0, 0);
        __syncthreads();               // all reads done before next overwrite
    }

    if (MODE == 1) {
        _Float16* outp = (which == 0) ? (_Float16*)o0
                        : (which == 1) ? (_Float16*)o1 : (_Float16*)o2;
        const float scale = (which == 0) ? 0.015625f : 1.0f;   // Q /= 64
#pragma unroll
        for (int i = 0; i < 4; ++i)
#pragma unroll
            for (int j = 0; j < 4; ++j) {
                int n  = nl + wc * 64 + j * 16 + l15;
                int hh = n >> 6, d = n & 63;
#pragma unroll
                for (int r = 0; r < 4; ++r) {
                    int m  = m0 + wr * 64 + i * 16 + lg * 4 + r;
                    int b_ = m >> 10, t_ = m & 1023;
                    outp[(((size_t)(b_ * NH + hh)) * SEQ + t_) * DH + d] =
                        (_Float16)(acc[i][j][r] * scale);
                }
            }
    } else {
        float* outp = (float*)o0;
#pragma unroll
        for (int i = 0; i < 4; ++i)
#pragma unroll
            for (int j = 0; j < 4; ++j) {
                int n = nl + wc * 64 + j * 16 + l15;
                float bz = bias[n];
#pragma unroll
                for (int r = 0; r < 4; ++r) {
                    int m = m0 + wr * 64 + i * 16 + lg * 4 + r;
                    outp[(size_t)m * DM + n] = acc[i][j][r] + bz;
                }
            }
    }
}

// ---------------------------------------------------------------------------
// V [bh][1024 t][64 d] f16  ->  Vt [bh][64 d][1024 t] f16
// ---------------------------------------------------------------------------
__global__ __launch_bounds__(256) void vtranspose(const _Float16* __restrict__ V,
                                                  _Float16* __restrict__ Vt)
{
    __shared__ _Float16 tile[64][72];
    const int bh = blockIdx.y;
    const int t0 = blockIdx.x * 64;
    const int tid = threadIdx.x;
    const int r = tid >> 3;          // 0..31
    const int c = (tid & 7) * 8;     // 0..56
    const size_t base = (size_t)bh * (SEQ * DH);
#pragma unroll
    for (int p = 0; p < 2; ++p) {
        int row = r + p * 32;
        *(f16x8*)&tile[row][c] = *(const f16x8*)&V[base + (size_t)(t0 + row) * DH + c];
    }
    __syncthreads();
#pragma unroll
    for (int p = 0; p < 2; ++p) {
        int d = r + p * 32;
        f16x8 vv;
#pragma unroll
        for (int i = 0; i < 8; ++i) vv[i] = tile[c + i][d];
        *(f16x8*)&Vt[base + (size_t)d * SEQ + t0 + c] = vv;
    }
}

// ---------------------------------------------------------------------------
// Flash attention, f16 MFMA, causal + rel-pos bias, SWAPPED-OPERAND form.
// Grid (8 pairs, 64 bh), 512 threads = 8 waves, NO intra-loop barriers.
// Wave w: qt = (w<4) ? pr : 15-pr, q-rows qr0 = qt*64 + (w&3)*16.
//
// QK^T computed as mfma(K, Q): D[(lg,r)=kv][l15=q] -> each lane holds S for
// ONE q-row (q = qr0+l15) x 16 kv slots (kv = kt*64 + st*16 + lg*4 + r).
// Softmax: 15 in-lane fmax + 2 shfl_xor (16,32); m/l/corr are LANE-LOCAL.
// PV computed as mfma(V, P): accT[(lg,r)=dh][l15=q] -> rescale + epilogue
// divide lane-local, zero shuffles. P routed via 4x8B LDS writes/tile.
// Bias: extended LDS table rpb2[1152] = rpb/64, idx>1023 -> -1e30 (auto mask;
// every q-row has >=1 valid kv in every processed tile so row max is finite).
// ---------------------------------------------------------------------------
__global__ __launch_bounds__(512) void attn_mfma(
    const _Float16* __restrict__ Q,   // [bh][1024][64], pre-scaled by 1/64
    const _Float16* __restrict__ K,   // [bh][1024][64]
    const _Float16* __restrict__ Vt,  // [bh][64][1024]
    const float* __restrict__ rpb,    // [16][1024]
    _Float16* __restrict__ ao)        // [b][t][h*64+d] f16
{
    const int pr  = blockIdx.x;       // 0..7
    const int bh  = blockIdx.y;       // 0..63
    const int b_  = bh >> 4;
    const int h_  = bh & 15;
    const int tid = threadIdx.x;
    const int w   = tid >> 6;         // wave 0..7
    const int ln  = tid & 63;
    const int l15 = ln & 15;
    const int lg  = ln >> 4;          // 0..3

    __shared__ _Float16 Pb[8][16][72];   // per-wave P buffer (18.4 KB)
    __shared__ float rpb2[1152];         // extended bias table (4.5 KB)

    // stage bias table: entries 0..1023 = rpb[h]/64; 1024..1151 = -1e30
    {
        float2 t = *(const float2*)&rpb[h_ * SEQ + tid * 2];
        t.x *= 0.015625f; t.y *= 0.015625f;
        *(float2*)&rpb2[tid * 2] = t;
        if (tid < 128) rpb2[1024 + tid] = -1e30f;
    }
    __syncthreads();                  // only barrier in the kernel

    const size_t qkb = (size_t)bh * (SEQ * DH);
    const int qt  = (w < 4) ? pr : (15 - pr);
    const int qr0 = qt * 64 + (w & 3) * 16;
    const int i_  = qr0 + l15;        // this lane's q-row

    f16x8 qa0, qa1;
    {
        const _Float16* qp = Q + qkb + (size_t)i_ * DH + lg * 8;
        qa0 = *(const f16x8*)qp;
        qa1 = *(const f16x8*)(qp + 32);
    }
    f32x4 accT[4];                    // accT[dt][r]: O[q=i_][dh=dt*16+lg*4+r]
#pragma unroll
    for (int dt = 0; dt < 4; ++dt) accT[dt] = (f32x4){0.f, 0.f, 0.f, 0.f};
    float m = -INFINITY, l = 0.f;

#pragma unroll 1
    for (int kt = 0; kt <= qt; ++kt) {
        // ---- S^T = K Q^T: lane holds S[q=i_][kv = kt*64+st*16+lg*4+r] ----
        const _Float16* kp = K + qkb + (size_t)(kt * 64 + l15) * DH + lg * 8;
        f32x4 sv[4];
#pragma unroll
        for (int st = 0; st < 4; ++st) {
            f16x8 kb0 = *(const f16x8*)(kp + st * 16 * DH);
            f16x8 kb1 = *(const f16x8*)(kp + st * 16 * DH + 32);
            f32x4 z = (f32x4){0.f, 0.f, 0.f, 0.f};
            z = __builtin_amdgcn_mfma_f32_16x16x32_f16(kb0, qa0, z, 0, 0, 0);
            z = __builtin_amdgcn_mfma_f32_16x16x32_f16(kb1, qa1, z, 0, 0, 0);
            sv[st] = z;
        }
        // ---- bias (+auto causal mask) + row max ----
        const int bidx = 1023 - i_ + kt * 64 + lg * 4;
        float tmax = -INFINITY;
#pragma unroll
        for (int st = 0; st < 4; ++st)
#pragma unroll
            for (int r = 0; r < 4; ++r) {
                float v = sv[st][r] + rpb2[bidx + st * 16 + r];
                sv[st][r] = v;
                tmax = fmaxf(tmax, v);
            }
        tmax = fmaxf(tmax, __shfl_xor(tmax, 16));
        tmax = fmaxf(tmax, __shfl_xor(tmax, 32));
        // ---- online softmax (lane-local m, l) ----
        float mn   = fmaxf(m, tmax);
        float corr = __expf(m - mn);
        m = mn;
        float ps = 0.f;
#pragma unroll
        for (int st = 0; st < 4; ++st)
#pragma unroll
            for (int r = 0; r < 4; ++r) {
                float p = __expf(sv[st][r] - mn);
                sv[st][r] = p;
                ps += p;
            }
        ps += __shfl_xor(ps, 16);
        ps += __shfl_xor(ps, 32);
        l = l * corr + ps;
#pragma unroll
        for (int dt = 0; dt < 4; ++dt) {
            accT[dt][0] *= corr; accT[dt][1] *= corr;
            accT[dt][2] *= corr; accT[dt][3] *= corr;
        }
        // ---- P -> LDS: row q=l15, 4x 8B packed writes ----
#pragma unroll
        for (int st = 0; st < 4; ++st) {
            f16x4 pk;
            pk[0] = (_Float16)sv[st][0]; pk[1] = (_Float16)sv[st][1];
            pk[2] = (_Float16)sv[st][2]; pk[3] = (_Float16)sv[st][3];
            *(f16x4*)&Pb[w][l15][st * 16 + lg * 4] = pk;
        }
        // same-wave write->read, no barrier (validated pattern)
        f16x8 pf0 = *(const f16x8*)&Pb[w][l15][lg * 8];
        f16x8 pf1 = *(const f16x8*)&Pb[w][l15][32 + lg * 8];
        // ---- O^T += V^T P^T : accT[dt] over dh rows, q cols ----
        const _Float16* vp = Vt + qkb + (size_t)l15 * SEQ + kt * 64 + lg * 8;
#pragma unroll
        for (int dt = 0; dt < 4; ++dt) {
            f16x8 vb0 = *(const f16x8*)(vp + dt * 16 * SEQ);
            f16x8 vb1 = *(const f16x8*)(vp + dt * 16 * SEQ + 32);
            accT[dt] = __builtin_amdgcn_mfma_f32_16x16x32_f16(vb0, pf0, accT[dt], 0, 0, 0);
            accT[dt] = __builtin_amdgcn_mfma_f32_16x16x32_f16(vb1, pf1, accT[dt], 0, 0, 0);
        }
    }
    // ---- epilogue: lane-local divide, packed 8B stores ----
    float inv = 1.f / l;
    _Float16* aop = ao + ((size_t)(b_ * SEQ + i_)) * DM + h_ * DH + lg * 4;
#pragma unroll
    for (int dt = 0; dt < 4; ++dt) {
        f16x4 o4;
        o4[0] = (_Float16)(accT[dt][0] * inv);
        o4[1] = (_Float16)(accT[dt][1] * inv);
        o4[2] = (_Float16)(accT[dt][2] * inv);
        o4[3] = (_Float16)(accT[dt][3] * inv);
        *(f16x4*)&aop[dt * 16] = o4;
    }
}

// ---------------------------------------------------------------------------
extern "C" void kernel_launch(void* const* d_in, const int* in_sizes, int n_in,
                              void* d_out, int out_size, void* d_ws, size_t ws_size,
                              hipStream_t stream)
{
    (void)in_sizes; (void)n_in; (void)out_size; (void)ws_size;
    const float* x   = (const float*)d_in[0];
    const float* Wq  = (const float*)d_in[1];
    const float* Wk  = (const float*)d_in[2];
    const float* Wv  = (const float*)d_in[3];
    const float* Wo  = (const float*)d_in[4];
    const float* bo  = (const float*)d_in[5];
    const float* rpb = (const float*)d_in[6];
    float* out = (float*)d_out;

    char* ws = (char*)d_ws;
    _Float16* xh  = (_Float16*)(ws);                  // 8 MB
    _Float16* q   = (_Float16*)(ws + (8u  << 20));    // 8 MB
    _Float16* k   = (_Float16*)(ws + (16u << 20));    // 8 MB
    _Float16* v   = (_Float16*)(ws + (24u << 20));    // 8 MB
    _Float16* vt  = (_Float16*)(ws + (32u << 20));    // 8 MB
    _Float16* aoh = (_Float16*)(ws + (40u << 20));    // 8 MB
    _Float16* wqt = (_Float16*)(ws + (48u << 20));    // 2 MB
    _Float16* wkt = (_Float16*)(ws + (50u << 20));    // 2 MB
    _Float16* wvt = (_Float16*)(ws + (52u << 20));    // 2 MB
    _Float16* wot = (_Float16*)(ws + (54u << 20));    // 2 MB

    cvt_x<<<2048, 256, 0, stream>>>(x, xh, BT * DM / 4);
    cvt_wT<<<dim3(16, 16, 4), 256, 0, stream>>>(Wq, Wk, Wv, Wo, wqt, wkt, wvt, wot);
    gemm_mfma<1><<<dim3(24, 32), 256, 0, stream>>>(xh, wqt, wkt, wvt, q, k, v, nullptr);
    vtranspose<<<dim3(SEQ / 64, BATCH * NH), 256, 0, stream>>>(v, vt);
    attn_mfma<<<dim3(8, BATCH * NH), 512, 0, stream>>>(q, k, vt, rpb, aoh);
    gemm_mfma<0><<<dim3(8, 32), 256, 0, stream>>>(aoh, wot, nullptr, nullptr, out, nullptr, nullptr, bo);
}